// Round 2
// baseline (265.472 us; speedup 1.0000x reference)
//
#include <hip/hip_runtime.h>

#define BLOCK 256

// ln(x) via v_log_f32 (log2, ~1 ulp) * ln2. Inputs here are >= ~5e-3, well
// away from denormal trouble. Absolute output threshold is 0.675 on values
// up to ~454 -> ~1.5e-3 relative budget; these approximations are ~1e-7.
__device__ __forceinline__ float fast_ln(float x) {
    return 0.69314718056f * __builtin_amdgcn_logf(x);
}
__device__ __forceinline__ float fast_rcp(float x) {
    return __builtin_amdgcn_rcpf(x);
}
__device__ __forceinline__ float fast_rsq(float x) {
    return __builtin_amdgcn_rsqf(x);
}

// ds_bpermute_b32: dst lane i <- src register of lane (addr>>2).
// Pure crossbar: no LDS storage touched, no bank conflicts ever — replaces
// the random ds_read_b128 gathers that averaged ~15 conflict cyc/instr
// (SQ_LDS_BANK_CONFLICT 5.77M at baseline). N_RELS == 64 == wavefront size,
// so lane l holds M[l]/beta[l] and M[r] is a 12x bpermute.
__device__ __forceinline__ float bperm(int ab, float v) {
    return __int_as_float(__builtin_amdgcn_ds_bpermute(ab, __float_as_int(v)));
}

// Faithful sparsemax for d=3 (Martins & Astudillo 2016), matching the
// reference: sort desc, cumsum, ksup = sum of support booleans,
// tau = (cs[ksup-1]-1)/ksup, out = max(z - tau, 0).
__device__ __forceinline__ void sparsemax3(float z0, float z1, float z2,
                                           float& o0, float& o1, float& o2) {
    float lo01 = fminf(z0, z1), hi01 = fmaxf(z0, z1);
    float s2 = fminf(lo01, z2);          // min of all
    float mx = fmaxf(lo01, z2);
    float s0 = fmaxf(hi01, mx);          // max of all
    float s1 = fminf(hi01, mx);          // middle
    float cs2 = s0 + s1;
    float cs3 = cs2 + s2;
    // k=1 support condition (1 + s0 > s0) is always true.
    bool k2 = (1.0f + 2.0f * s1 > cs2);
    bool k3 = (1.0f + 3.0f * s2 > cs3);
    int k = 1 + (int)k2 + (int)k3;
    float csk = (k == 1) ? s0 : ((k == 2) ? cs2 : cs3);
    float rk  = (k == 1) ? 1.0f : ((k == 2) ? 0.5f : 0.33333334f);
    float tau = (csk - 1.0f) * rk;
    o0 = fmaxf(z0 - tau, 0.0f);
    o1 = fmaxf(z1 - tau, 0.0f);
    o2 = fmaxf(z2 - tau, 0.0f);
}

__device__ __forceinline__ void edge_core(
    float p0, float p1, float p2,
    float q0, float q1, float q2,
    float m00, float m01, float m02,
    float m10, float m11, float m12,
    float m20, float m21, float m22,
    float b0, float b1, float b2,
    float zeps, float sf,
    float& a0o, float& a1o, float& a2o)
{
    float c0 = m00 * q0 + m01 * q1 + m02 * q2;
    float c1 = m10 * q0 + m11 * q1 + m12 * q2;
    float c2 = m20 * q0 + m21 * q1 + m22 * q2;
    sparsemax3(c0, c1, c2, c0, c1, c2);
    // The reference applies sparsemax to c TWICE. Sparsemax is a Euclidean
    // projection onto the simplex => exactly idempotent; reapplying changes
    // c only by ~ulp (tau' = ((1 +- eps) - 1)/k). Dropped: ~15 VALU ops/edge
    // saved against a 0.675 absmax budget (headroom was 0.55).
    sparsemax3(p0, p1, p2, p0, p1, p2);
    // (1-b)*p + b*c == p + b*(c-p) up to ulp; one fma instead of mul+fma.
    float a0 = p0 + b0 * (c0 - p0);
    float a1 = p1 + b1 * (c1 - p1);
    float a2 = p2 + b2 * (c2 - p2);
    // scale(): entropy of clamped, normalized mixture
    float z0 = fmaxf(p0 + c0, zeps);
    float z1 = fmaxf(p1 + c1, zeps);
    float z2 = fmaxf(p2 + c2, zeps);
    float rs = fast_rcp(z0 + z1 + z2);
    z0 *= rs; z1 *= rs; z2 *= rs;
    float ent = -(z0 * fast_ln(z0) + z1 * fast_ln(z1) + z2 * fast_ln(z2));
    // cosine similarity between p and c; p,c on simplex -> |p|^2,|c|^2 >= 1/3,
    // the reference's 1e-10 guard never binds; guard the squared product.
    float dot = p0 * c0 + p1 * c1 + p2 * c2;
    float pp = p0 * p0 + p1 * p1 + p2 * p2;
    float cc = c0 * c0 + c1 * c1 + c2 * c2;
    float cosv = 0.1f + dot * fast_rsq(fmaxf(pp * cc, 1e-20f));
    float scale = sf * cosv * fast_rcp(ent);
    a0o = fmaxf(a0 * scale, 0.001f);
    a1o = fmaxf(a1 * scale, 0.001f);
    a2o = fmaxf(a2 * scale, 0.001f);
}

__global__ __launch_bounds__(BLOCK) void alpha_kernel(
    const float* __restrict__ prnt, const float* __restrict__ child,
    const float* __restrict__ Mg, const float* __restrict__ betag,
    const float* __restrict__ zeps_p, const float* __restrict__ sf_p,
    const int* __restrict__ rels, float* __restrict__ out, int n_edges)
{
    // Lane-resident parameter table: lane l holds M[l] (9 regs) + beta[l]
    // (3 regs). M/beta total 2.3 KB -> L1-resident after the first wave;
    // this load is once per thread, amortized over 4 edges.
    const int lane = threadIdx.x & 63;
    float mt[9], bt[3];
    {
        const float* mr = Mg + lane * 9;
#pragma unroll
        for (int k = 0; k < 9; ++k) mt[k] = mr[k];
        const float* br = betag + lane * 3;
#pragma unroll
        for (int k = 0; k < 3; ++k) bt[k] = br[k];
    }

    const float zeps = zeps_p[0];
    const float sf   = sf_p[0];
    const int nt4 = n_edges >> 2;          // full groups of 4 edges
    const int t = blockIdx.x * BLOCK + threadIdx.x;

    if (nt4 > 0) {
        // bpermute reads the SOURCE lane's register, so this whole region must
        // run with all lanes active: clamp the index instead of branching, and
        // guard only the stores. Extra threads (< 256) do redundant compute.
        const int tc = min(t, nt4 - 1);
        const float4* p4 = (const float4*)prnt;
        const float4* c4 = (const float4*)child;
        int4 r4 = ((const int4*)rels)[tc];
        float4 pa = p4[3 * tc + 0], pb = p4[3 * tc + 1], pc = p4[3 * tc + 2];
        float4 ca = c4[3 * tc + 0], cb = c4[3 * tc + 1], cc = c4[3 * tc + 2];
        float P[12] = {pa.x, pa.y, pa.z, pa.w, pb.x, pb.y, pb.z, pb.w,
                       pc.x, pc.y, pc.z, pc.w};
        float C[12] = {ca.x, ca.y, ca.z, ca.w, cb.x, cb.y, cb.z, cb.w,
                       cc.x, cc.y, cc.z, cc.w};
        int R[4] = {r4.x, r4.y, r4.z, r4.w};
        float O[12];
#pragma unroll
        for (int e = 0; e < 4; ++e) {
            int ab = R[e] << 2;            // byte index for bpermute
            float g0 = bperm(ab, mt[0]), g1 = bperm(ab, mt[1]), g2 = bperm(ab, mt[2]);
            float g3 = bperm(ab, mt[3]), g4 = bperm(ab, mt[4]), g5 = bperm(ab, mt[5]);
            float g6 = bperm(ab, mt[6]), g7 = bperm(ab, mt[7]), g8 = bperm(ab, mt[8]);
            float h0 = bperm(ab, bt[0]), h1 = bperm(ab, bt[1]), h2 = bperm(ab, bt[2]);
            edge_core(P[3 * e], P[3 * e + 1], P[3 * e + 2],
                      C[3 * e], C[3 * e + 1], C[3 * e + 2],
                      g0, g1, g2, g3, g4, g5, g6, g7, g8,
                      h0, h1, h2, zeps, sf,
                      O[3 * e], O[3 * e + 1], O[3 * e + 2]);
        }
        if (t < nt4) {
            float4* o4 = (float4*)out;
            float4 oa = {O[0], O[1], O[2],  O[3]};
            float4 ob = {O[4], O[5], O[6],  O[7]};
            float4 oc = {O[8], O[9], O[10], O[11]};
            o4[3 * t + 0] = oa;
            o4[3 * t + 1] = ob;
            o4[3 * t + 2] = oc;
        }
        if (t == nt4) {
            // scalar tail for n_edges % 4 edges (none for N=8M, defensive).
            // Divergent region: NO cross-lane ops — read M/beta from global.
            for (int e = nt4 * 4; e < n_edges; ++e) {
                int r = rels[e];
                const float* m = Mg + r * 9;
                const float* b = betag + r * 3;
                float a0, a1, a2;
                edge_core(prnt[3 * e], prnt[3 * e + 1], prnt[3 * e + 2],
                          child[3 * e], child[3 * e + 1], child[3 * e + 2],
                          m[0], m[1], m[2], m[3], m[4], m[5], m[6], m[7], m[8],
                          b[0], b[1], b[2], zeps, sf, a0, a1, a2);
                out[3 * e] = a0; out[3 * e + 1] = a1; out[3 * e + 2] = a2;
            }
        }
    }
}

extern "C" void kernel_launch(void* const* d_in, const int* in_sizes, int n_in,
                              void* d_out, int out_size, void* d_ws, size_t ws_size,
                              hipStream_t stream) {
    const float* prnt  = (const float*)d_in[0];
    const float* child = (const float*)d_in[1];
    const float* Mg    = (const float*)d_in[2];
    const float* betag = (const float*)d_in[3];
    const float* zeps  = (const float*)d_in[4];
    const float* sf    = (const float*)d_in[5];
    const int*   rels  = (const int*)d_in[6];
    float* out = (float*)d_out;

    int n_edges = in_sizes[0] / 3;
    int nthreads = (n_edges >> 2) + 1;           // +1 thread for scalar tail
    int nblocks = (nthreads + BLOCK - 1) / BLOCK;
    alpha_kernel<<<nblocks, BLOCK, 0, stream>>>(
        prnt, child, Mg, betag, zeps, sf, rels, out, n_edges);
}